// Round 13
// baseline (151.841 us; speedup 1.0000x reference)
//
#include <hip/hip_runtime.h>
#include <hip/hip_bf16.h>
#include <math.h>

// ---------------------------------------------------------------------------
// Sketched CNN-MNIST forward, MFMA end-to-end.
// Weights AND h2 stored FRAGMENT-MAJOR so every MFMA operand load is one
// coalesced 1 KB wave transaction from global:
//   wc*f/W3f: element (n=l15, k=quad*8+j) at [tile][lane][8]
//   h2f:      element (img, k) at [img>>4][k>>5][((k>>3)&3)*16+(img&15)][k&7]
// conv: 4 img/block, 8 waves, 3 blocks/CU (R11 shape — best measured 43 µs).
// fc1:  SPLIT-K, grid (B/16, 2): each block does a 16-kt half of K for all
//       512 cols; no LDS -> 2 blocks/CU = 32 waves/CU (fc was latency-bound
//       at 16 waves/CU: 24 GB/s/CU observed vs 135 available). f32 partials
//       to global.
// fc2:  relu(p0+p1+b3) on the fly + fc2 + log_softmax; fc2w staged in LDS.
// ---------------------------------------------------------------------------

typedef __attribute__((ext_vector_type(8))) short bf16x8;
typedef __attribute__((ext_vector_type(4))) float f32x4;

static __device__ inline ushort f2bfu(float v) {
    union { __hip_bfloat16 h; ushort u; } cv;
    cv.h = __float2bfloat16(v);
    return cv.u;
}

// ws layout (bytes):
//   wc1f bf16 [2 nt][64 lane][8]   frag-major      [0,       2048)
//   wc1s bf16 [2 nt][64 lane][8]   shifted         [2048,    4096)
//   wc2f bf16 [25 tap][4 nt][64 lane][8ic]         [4096,    106496)
//   W3f  bf16 [32 ntile][32 kt][64 lane][8]        [106496,  1155072)
//   h2f  bf16 [B/16][32 kt][64 lane][8]            [1155072, +B*2048)
//   p    f32  [2][B][512]  fc1 K-split partials    [.., +2*B*2048)

__global__ __launch_bounds__(256)
void k_reconstruct(const float* __restrict__ w1, const float* __restrict__ w2,
                   const float* __restrict__ w3,
                   const int* __restrict__ hi1, const int* __restrict__ hi2,
                   const int* __restrict__ hi3,
                   const float* __restrict__ s1, const float* __restrict__ s2,
                   const float* __restrict__ s3,
                   __hip_bfloat16* __restrict__ wc1f,
                   __hip_bfloat16* __restrict__ wc1s,
                   __hip_bfloat16* __restrict__ wc2f,
                   __hip_bfloat16* __restrict__ W3f) {
    const int t = blockIdx.x * blockDim.x + threadIdx.x;
    bf16x8 o;
    if (t < 256) {                         // conv1 normal (t<128) / shifted
        const bool shifted = t >= 128;
        const int u = t & 127;
        const int nt = u >> 6, lane = u & 63;
        const int quad = lane >> 4, l15 = lane & 15;
        const int oc = nt * 16 + l15;
        #pragma unroll
        for (int j = 0; j < 8; ++j) {
            int tt = quad * 8 + j;
            int ki = (tt * 43) >> 8;       // tt / 6
            int kj = tt - 6 * ki;
            float v = 0.f;
            if (!shifted && ki < 5 && kj < 5) {
                int f = ki * 5 + kj;
                v = w1[oc * 128 + hi1[f]] * s1[f];
            } else if (shifted && ki < 5 && kj >= 1 && kj <= 5) {
                int f = ki * 5 + (kj - 1);
                v = w1[oc * 128 + hi1[f]] * s1[f];
            }
            o[j] = (short)f2bfu(v);
        }
        *(bf16x8*)((ushort*)(shifted ? wc1s : wc1f) + (size_t)u * 8) = o;
    } else if (t < 6656) {                 // conv2: [tap][nt][lane][8ic]
        const int u = t - 256;
        const int l15 = u & 15, quad = (u >> 4) & 3;
        const int ntA = (u >> 6) & 3, tap = u >> 8;
        const int oc = ntA * 16 + l15;
        #pragma unroll
        for (int j = 0; j < 8; ++j) {
            int ic = quad * 8 + j;
            int f = ic * 25 + tap;
            o[j] = (short)f2bfu(w2[oc * 128 + hi2[f]] * s2[f]);
        }
        *(bf16x8*)((ushort*)wc2f + (size_t)u * 8) = o;
    } else if (t < 72192) {                // fc1: [ntile][kt][lane][8]
        const int u = t - 6656;
        const int l15 = u & 15, quad = (u >> 4) & 3;
        const int kt = (u >> 6) & 31, ntile = u >> 11;
        const int n = ntile * 16 + l15;
        #pragma unroll
        for (int j = 0; j < 8; ++j) {
            int k = kt * 32 + quad * 8 + j;
            o[j] = (short)f2bfu(w3[n * 128 + hi3[k]] * s3[k]);
        }
        *(bf16x8*)((ushort*)W3f + (size_t)u * 8) = o;
    }
}

// 4 images per block, 8 waves, 3 blocks/CU (LDS 43.6 KB) — R11 shape.
// h1 layout: section s = img*4 + (ic>>3); s_h1[s*1160 + pos*8 + (ic&7)].
__global__ __launch_bounds__(512, 6)
void k_conv(const float* __restrict__ x,
            const __hip_bfloat16* __restrict__ wc1f,
            const __hip_bfloat16* __restrict__ wc1s,
            const __hip_bfloat16* __restrict__ wc2f,
            const float* __restrict__ b1, const float* __restrict__ b2,
            ushort* __restrict__ h2f) {
    __shared__ __align__(16) ushort s_xb[4 * 816];     // bf16 images (+pad)
    __shared__ __align__(16) ushort s_h1[16 * 1160];   // sectioned, 37.1 KB

    const int tid = threadIdx.x;
    const int b0 = blockIdx.x * 4;
    const int wave = tid >> 6, lane = tid & 63;
    const int l15 = lane & 15, quad = lane >> 4;

    // ---- stage 4 images as bf16 (coalesced float4) ----
    {
        const float4* xg = (const float4*)(x + (size_t)b0 * 784);
        for (int i = tid; i < 784; i += 512) {
            float4 v = xg[i];
            int img = i / 196;
            int pos = (i - img * 196) * 4;
            ushort* dst = &s_xb[img * 816 + pos];
            dst[0] = f2bfu(v.x); dst[1] = f2bfu(v.y);
            dst[2] = f2bfu(v.z); dst[3] = f2bfu(v.w);
        }
        if (tid < 128) {                    // zero pad (read by pad taps, w=0)
            int img = tid >> 5, k = tid & 31;
            s_xb[img * 816 + 784 + k] = 0;
        }
    }

    // conv1 B-fragments (frag-major: coalesced 1 KB wave loads)
    bf16x8 bw1[2], bw1s[2];
    float bb1[2];
    #pragma unroll
    for (int nt = 0; nt < 2; ++nt) {
        bw1[nt]  = *(const bf16x8*)((const ushort*)wc1f + (nt * 64 + lane) * 8);
        bw1s[nt] = *(const bf16x8*)((const ushort*)wc1s + (nt * 64 + lane) * 8);
        bb1[nt] = b1[nt * 16 + l15];
    }
    __syncthreads();

    // ---- conv1 via MFMA: wave = (img, half). M=576 pool-grouped, N=32 ----
    {
        const int img = wave >> 1, half = wave & 1;
        const int sub = l15 & 3;
        const ushort* srcImg = s_xb + img * 816;
        int offr[4];
        #pragma unroll
        for (int r = 0; r < 4; ++r) {
            int t = quad * 8 + 2 * r;          // even
            int row = (t * 43) >> 8;           // t / 6
            int col = t - 6 * row;             // even
            offr[r] = row * 28 + col;          // even
        }
        const int g0 = l15 >> 3, r0 = l15 & 7;
        #pragma unroll
        for (int ii = 0; ii < 18; ++ii) {
            const int i = half * 18 + ii;
            const int pb = 4 * i + (l15 >> 2);
            const int pi = (pb * 171) >> 11;   // pb / 12
            const int pj = pb - 12 * pi;
            const int base_e = (2 * pi + (sub >> 1)) * 28 + 2 * pj;   // even
            const ushort* p0 = srcImg + base_e;
            union { bf16x8 v; uint u[4]; } A;
            A.u[0] = *(const uint*)(p0 + offr[0]);
            A.u[1] = *(const uint*)(p0 + offr[1]);
            A.u[2] = *(const uint*)(p0 + offr[2]);
            A.u[3] = *(const uint*)(p0 + offr[3]);
            f32x4 z = {0.f, 0.f, 0.f, 0.f};
            f32x4 ce0 = __builtin_amdgcn_mfma_f32_16x16x32_bf16(A.v, bw1[0],  z, 0, 0, 0);
            f32x4 co0 = __builtin_amdgcn_mfma_f32_16x16x32_bf16(A.v, bw1s[0], z, 0, 0, 0);
            f32x4 ce1 = __builtin_amdgcn_mfma_f32_16x16x32_bf16(A.v, bw1[1],  z, 0, 0, 0);
            f32x4 co1 = __builtin_amdgcn_mfma_f32_16x16x32_bf16(A.v, bw1s[1], z, 0, 0, 0);
            const int pbo = 4 * i + quad;
            float m0 = fmaxf(fmaxf(ce0[0], co0[1]), fmaxf(ce0[2], co0[3]));
            float m1 = fmaxf(fmaxf(ce1[0], co1[1]), fmaxf(ce1[2], co1[3]));
            s_h1[(img * 4 + g0) * 1160 + pbo * 8 + r0]     = f2bfu(fmaxf(m0 + bb1[0], 0.f));
            s_h1[(img * 4 + 2 + g0) * 1160 + pbo * 8 + r0] = f2bfu(fmaxf(m1 + bb1[1], 0.f));
        }
    }
    __syncthreads();

    // ---- conv2: 25 tap-GEMMs, K=ic=32; wave = (pool-row, n-half), 4 images
    //      4 A ds_reads + 2 coalesced B loads -> 8 MFMA per tap ----
    const int pr = wave >> 1, nh = wave & 1;
    const int sub2 = l15 & 3;
    const int ci2 = 2 * pr + (sub2 >> 1);
    const int cj2 = 2 * (l15 >> 2) + (sub2 & 1);
    const int posBase = (ci2 * 12 + cj2) * 8;

    f32x4 acc[4][2];                       // [img][ntl]
    float bb2[2];
    #pragma unroll
    for (int ntl = 0; ntl < 2; ++ntl) {
        bb2[ntl] = b2[(nh * 2 + ntl) * 16 + l15];
        #pragma unroll
        for (int img = 0; img < 4; ++img)
            acc[img][ntl] = (f32x4){0.f, 0.f, 0.f, 0.f};
    }

    #pragma unroll
    for (int tap = 0; tap < 25; ++tap) {
        const int ki = tap / 5, kj = tap % 5;          // compile-time
        const int off = (ki * 12 + kj) * 8;
        bf16x8 a[4];
        #pragma unroll
        for (int img = 0; img < 4; ++img)
            a[img] = *(const bf16x8*)&s_h1[(img * 4 + quad) * 1160 + posBase + off];
        #pragma unroll
        for (int ntl = 0; ntl < 2; ++ntl) {
            bf16x8 bf = *(const bf16x8*)((const ushort*)wc2f +
                          ((tap * 4 + nh * 2 + ntl) * 64 + lane) * 8);
            #pragma unroll
            for (int img = 0; img < 4; ++img)
                acc[img][ntl] = __builtin_amdgcn_mfma_f32_16x16x32_bf16(
                    a[img], bf, acc[img][ntl], 0, 0, 0);
        }
    }

    // D rows m = quad*4+r -> (pool row = pr, pool col = quad), max over r.
    // Write h2 FRAGMENT-MAJOR.
    #pragma unroll
    for (int img = 0; img < 4; ++img) {
        const int img_g = b0 + img;
        const size_t base = (size_t)(img_g >> 4) * 16384 + (img_g & 15) * 8;
        #pragma unroll
        for (int ntl = 0; ntl < 2; ++ntl) {
            f32x4 c = acc[img][ntl];
            float m = fmaxf(fmaxf(c[0], c[1]), fmaxf(c[2], c[3]));
            float v = fmaxf(m + bb2[ntl], 0.f);
            const int k = (nh * 2 + ntl) * 256 + l15 * 16 + pr * 4 + quad;
            h2f[base + (size_t)(k >> 5) * 512 + ((k >> 3) & 3) * 128 + (k & 7)] =
                f2bfu(v);
        }
    }
}

// fc1 SPLIT-K: grid (B/16, 2). Block = 16 images x 512 cols x 16-kt half.
// 1024 thr = 16 waves x 32-col strips; no LDS -> 2 blocks/CU = 32 waves/CU.
// A/B frag-major straight from global; f32 partials (no bias/relu) to p.
__global__ __launch_bounds__(1024)
void k_fc1(const ushort* __restrict__ h2f, const __hip_bfloat16* __restrict__ W3f,
           float* __restrict__ p, int pstride) {
    const int tid = threadIdx.x;
    const int wave = tid >> 6, lane = tid & 63;
    const int l15 = lane & 15, quad = lane >> 4;
    const int mBase = blockIdx.x * 16;
    const int k0 = blockIdx.y * 16;        // kt half

    f32x4 acc[2];
    acc[0] = (f32x4){0.f, 0.f, 0.f, 0.f};
    acc[1] = (f32x4){0.f, 0.f, 0.f, 0.f};

    const ushort* aP  = h2f + (size_t)blockIdx.x * 16384 + (size_t)k0 * 512 + lane * 8;
    const ushort* bP0 = (const ushort*)W3f + ((size_t)(wave * 2)     * 16384
                                              + (size_t)k0 * 512 + lane * 8);
    const ushort* bP1 = (const ushort*)W3f + ((size_t)(wave * 2 + 1) * 16384
                                              + (size_t)k0 * 512 + lane * 8);
    #pragma unroll 4
    for (int kt = 0; kt < 16; ++kt) {
        bf16x8 a   = *(const bf16x8*)(aP + kt * 512);
        bf16x8 bf0 = *(const bf16x8*)(bP0 + kt * 512);
        bf16x8 bf1 = *(const bf16x8*)(bP1 + kt * 512);
        acc[0] = __builtin_amdgcn_mfma_f32_16x16x32_bf16(a, bf0, acc[0], 0, 0, 0);
        acc[1] = __builtin_amdgcn_mfma_f32_16x16x32_bf16(a, bf1, acc[1], 0, 0, 0);
    }

    float* pOut = p + (size_t)blockIdx.y * pstride;
    #pragma unroll
    for (int ntl = 0; ntl < 2; ++ntl) {
        const int col = wave * 32 + ntl * 16 + l15;
        #pragma unroll
        for (int r = 0; r < 4; ++r)
            pOut[(size_t)(mBase + quad * 4 + r) * 512 + col] = acc[ntl][r];
    }
}

// fc2 + log_softmax: 16 images/block, 256 thr; h3 = relu(p0+p1+b3) on the fly;
// fc2w staged in LDS; 16-lane shuffle reduce.
__global__ __launch_bounds__(256)
void k_fc2(const float* __restrict__ p, int pstride,
           const float* __restrict__ b3, const float* __restrict__ fc2w,
           const float* __restrict__ fc2b, float* __restrict__ out) {
    __shared__ float s_w[5120];            // [10][512]

    const int tid = threadIdx.x;
    for (int i = tid; i < 1280; i += 256)
        ((float4*)s_w)[i] = ((const float4*)fc2w)[i];
    __syncthreads();

    const int m = tid >> 4, t16 = tid & 15;
    const int img = blockIdx.x * 16 + m;

    float acc[10];
    #pragma unroll
    for (int c = 0; c < 10; ++c) acc[c] = 0.f;
    #pragma unroll
    for (int kb = 0; kb < 8; ++kb) {
        const int k = kb * 64 + t16 * 4;
        float4 v0 = *(const float4*)&p[(size_t)img * 512 + k];
        float4 v1 = *(const float4*)&p[(size_t)pstride + (size_t)img * 512 + k];
        float4 bb = *(const float4*)&b3[k];
        float4 h;
        h.x = fmaxf(v0.x + v1.x + bb.x, 0.f);
        h.y = fmaxf(v0.y + v1.y + bb.y, 0.f);
        h.z = fmaxf(v0.z + v1.z + bb.z, 0.f);
        h.w = fmaxf(v0.w + v1.w + bb.w, 0.f);
        #pragma unroll
        for (int c = 0; c < 10; ++c) {
            float4 w = *(const float4*)&s_w[c * 512 + k];
            acc[c] += h.x * w.x + h.y * w.y + h.z * w.z + h.w * w.w;
        }
    }
    #pragma unroll
    for (int c = 0; c < 10; ++c) {
        acc[c] += __shfl_down(acc[c], 8, 16);
        acc[c] += __shfl_down(acc[c], 4, 16);
        acc[c] += __shfl_down(acc[c], 2, 16);
        acc[c] += __shfl_down(acc[c], 1, 16);
    }
    if (t16 == 0) {
        float l[10], mx = -1e30f;
        #pragma unroll
        for (int c = 0; c < 10; ++c) { l[c] = acc[c] + fc2b[c]; mx = fmaxf(mx, l[c]); }
        float sum = 0.f;
        #pragma unroll
        for (int c = 0; c < 10; ++c) sum += expf(l[c] - mx);
        float lse = mx + logf(sum);
        #pragma unroll
        for (int c = 0; c < 10; ++c)
            out[(size_t)img * 10 + c] = l[c] - lse;
    }
}

extern "C" void kernel_launch(void* const* d_in, const int* in_sizes, int n_in,
                              void* d_out, int out_size, void* d_ws, size_t ws_size,
                              hipStream_t stream) {
    const float* x    = (const float*)d_in[0];
    const int*   hi1  = (const int*)d_in[1];
    const int*   hi2  = (const int*)d_in[2];
    const int*   hi3  = (const int*)d_in[3];
    const float* s1   = (const float*)d_in[4];
    const float* s2   = (const float*)d_in[5];
    const float* s3   = (const float*)d_in[6];
    const float* w1   = (const float*)d_in[7];
    const float* b1   = (const float*)d_in[8];
    const float* w2   = (const float*)d_in[9];
    const float* b2   = (const float*)d_in[10];
    const float* w3   = (const float*)d_in[11];
    const float* b3   = (const float*)d_in[12];
    const float* fc2w = (const float*)d_in[13];
    const float* fc2b = (const float*)d_in[14];
    float* out = (float*)d_out;

    const int B = in_sizes[0] / 784;   // 4096

    char* ws = (char*)d_ws;
    __hip_bfloat16* wc1f = (__hip_bfloat16*)(ws + 0);
    __hip_bfloat16* wc1s = (__hip_bfloat16*)(ws + 2048);
    __hip_bfloat16* wc2f = (__hip_bfloat16*)(ws + 4096);
    __hip_bfloat16* W3f  = (__hip_bfloat16*)(ws + 106496);
    ushort*         h2f  = (ushort*)(ws + 1155072);
    float*          p    = (float*)(ws + 1155072 + (size_t)B * 2048);

    k_reconstruct<<<(72192 + 255) / 256, 256, 0, stream>>>(
        w1, w2, w3, hi1, hi2, hi3, s1, s2, s3, wc1f, wc1s, wc2f, W3f);
    k_conv<<<B / 4, 512, 0, stream>>>(x, wc1f, wc1s, wc2f, b1, b2, h2f);
    k_fc1<<<dim3(B / 16, 2), 1024, 0, stream>>>(h2f, W3f, p, B * 512);
    k_fc2<<<B / 16, 256, 0, stream>>>(p, B * 512, b3, fc2w, fc2b, out);
}

// Round 14
// 144.672 us; speedup vs baseline: 1.0496x; 1.0496x over previous
//
#include <hip/hip_runtime.h>
#include <hip/hip_bf16.h>
#include <math.h>

// ---------------------------------------------------------------------------
// Sketched CNN-MNIST forward, MFMA end-to-end.
// Weights AND h2 stored FRAGMENT-MAJOR so every MFMA operand load is one
// coalesced 1 KB wave transaction from global:
//   wc*f/W3f: element (n=l15, k=quad*8+j) at [tile][lane][8]
//   h2f:      element (img, k) at [img>>4][k>>5][((k>>3)&3)*16+(img&15)][k&7]
// conv: 4 img/block, 8 waves, 3 blocks/CU (best measured: 43.0 µs).
// fc:   R9 structure (best ledger): 1024 thr, 16 waves x 32-col strips, A/B
//       frag-major straight from global; NEW: K split in registers -> 4
//       independent MFMA chains of 16 per wave (ILP, same traffic);
//       fused fc2 + log_softmax, 1 image/wave.
// ---------------------------------------------------------------------------

typedef __attribute__((ext_vector_type(8))) short bf16x8;
typedef __attribute__((ext_vector_type(4))) float f32x4;

static __device__ inline ushort f2bfu(float v) {
    union { __hip_bfloat16 h; ushort u; } cv;
    cv.h = __float2bfloat16(v);
    return cv.u;
}

// ws layout (bytes):
//   wc1f bf16 [2 nt][64 lane][8]   frag-major      [0,       2048)
//   wc1s bf16 [2 nt][64 lane][8]   shifted         [2048,    4096)
//   wc2f bf16 [25 tap][4 nt][64 lane][8ic]         [4096,    106496)
//   W3f  bf16 [32 ntile][32 kt][64 lane][8]        [106496,  1155072)
//   h2f  bf16 [B/16][32 kt][64 lane][8]            [1155072, +B*2048)

__global__ __launch_bounds__(256)
void k_reconstruct(const float* __restrict__ w1, const float* __restrict__ w2,
                   const float* __restrict__ w3,
                   const int* __restrict__ hi1, const int* __restrict__ hi2,
                   const int* __restrict__ hi3,
                   const float* __restrict__ s1, const float* __restrict__ s2,
                   const float* __restrict__ s3,
                   __hip_bfloat16* __restrict__ wc1f,
                   __hip_bfloat16* __restrict__ wc1s,
                   __hip_bfloat16* __restrict__ wc2f,
                   __hip_bfloat16* __restrict__ W3f) {
    const int t = blockIdx.x * blockDim.x + threadIdx.x;
    bf16x8 o;
    if (t < 256) {                         // conv1 normal (t<128) / shifted
        const bool shifted = t >= 128;
        const int u = t & 127;
        const int nt = u >> 6, lane = u & 63;
        const int quad = lane >> 4, l15 = lane & 15;
        const int oc = nt * 16 + l15;
        #pragma unroll
        for (int j = 0; j < 8; ++j) {
            int tt = quad * 8 + j;
            int ki = (tt * 43) >> 8;       // tt / 6
            int kj = tt - 6 * ki;
            float v = 0.f;
            if (!shifted && ki < 5 && kj < 5) {
                int f = ki * 5 + kj;
                v = w1[oc * 128 + hi1[f]] * s1[f];
            } else if (shifted && ki < 5 && kj >= 1 && kj <= 5) {
                int f = ki * 5 + (kj - 1);
                v = w1[oc * 128 + hi1[f]] * s1[f];
            }
            o[j] = (short)f2bfu(v);
        }
        *(bf16x8*)((ushort*)(shifted ? wc1s : wc1f) + (size_t)u * 8) = o;
    } else if (t < 6656) {                 // conv2: [tap][nt][lane][8ic]
        const int u = t - 256;
        const int l15 = u & 15, quad = (u >> 4) & 3;
        const int ntA = (u >> 6) & 3, tap = u >> 8;
        const int oc = ntA * 16 + l15;
        #pragma unroll
        for (int j = 0; j < 8; ++j) {
            int ic = quad * 8 + j;
            int f = ic * 25 + tap;
            o[j] = (short)f2bfu(w2[oc * 128 + hi2[f]] * s2[f]);
        }
        *(bf16x8*)((ushort*)wc2f + (size_t)u * 8) = o;
    } else if (t < 72192) {                // fc1: [ntile][kt][lane][8]
        const int u = t - 6656;
        const int l15 = u & 15, quad = (u >> 4) & 3;
        const int kt = (u >> 6) & 31, ntile = u >> 11;
        const int n = ntile * 16 + l15;
        #pragma unroll
        for (int j = 0; j < 8; ++j) {
            int k = kt * 32 + quad * 8 + j;
            o[j] = (short)f2bfu(w3[n * 128 + hi3[k]] * s3[k]);
        }
        *(bf16x8*)((ushort*)W3f + (size_t)u * 8) = o;
    }
}

// 4 images per block, 8 waves, 3 blocks/CU (LDS 43.6 KB) — best measured.
// h1 layout: section s = img*4 + (ic>>3); s_h1[s*1160 + pos*8 + (ic&7)].
__global__ __launch_bounds__(512, 6)
void k_conv(const float* __restrict__ x,
            const __hip_bfloat16* __restrict__ wc1f,
            const __hip_bfloat16* __restrict__ wc1s,
            const __hip_bfloat16* __restrict__ wc2f,
            const float* __restrict__ b1, const float* __restrict__ b2,
            ushort* __restrict__ h2f) {
    __shared__ __align__(16) ushort s_xb[4 * 816];     // bf16 images (+pad)
    __shared__ __align__(16) ushort s_h1[16 * 1160];   // sectioned, 37.1 KB

    const int tid = threadIdx.x;
    const int b0 = blockIdx.x * 4;
    const int wave = tid >> 6, lane = tid & 63;
    const int l15 = lane & 15, quad = lane >> 4;

    // ---- stage 4 images as bf16 (coalesced float4) ----
    {
        const float4* xg = (const float4*)(x + (size_t)b0 * 784);
        for (int i = tid; i < 784; i += 512) {
            float4 v = xg[i];
            int img = i / 196;
            int pos = (i - img * 196) * 4;
            ushort* dst = &s_xb[img * 816 + pos];
            dst[0] = f2bfu(v.x); dst[1] = f2bfu(v.y);
            dst[2] = f2bfu(v.z); dst[3] = f2bfu(v.w);
        }
        if (tid < 128) {                    // zero pad (read by pad taps, w=0)
            int img = tid >> 5, k = tid & 31;
            s_xb[img * 816 + 784 + k] = 0;
        }
    }

    // conv1 B-fragments (frag-major: coalesced 1 KB wave loads)
    bf16x8 bw1[2], bw1s[2];
    float bb1[2];
    #pragma unroll
    for (int nt = 0; nt < 2; ++nt) {
        bw1[nt]  = *(const bf16x8*)((const ushort*)wc1f + (nt * 64 + lane) * 8);
        bw1s[nt] = *(const bf16x8*)((const ushort*)wc1s + (nt * 64 + lane) * 8);
        bb1[nt] = b1[nt * 16 + l15];
    }
    __syncthreads();

    // ---- conv1 via MFMA: wave = (img, half). M=576 pool-grouped, N=32 ----
    {
        const int img = wave >> 1, half = wave & 1;
        const int sub = l15 & 3;
        const ushort* srcImg = s_xb + img * 816;
        int offr[4];
        #pragma unroll
        for (int r = 0; r < 4; ++r) {
            int t = quad * 8 + 2 * r;          // even
            int row = (t * 43) >> 8;           // t / 6
            int col = t - 6 * row;             // even
            offr[r] = row * 28 + col;          // even
        }
        const int g0 = l15 >> 3, r0 = l15 & 7;
        #pragma unroll
        for (int ii = 0; ii < 18; ++ii) {
            const int i = half * 18 + ii;
            const int pb = 4 * i + (l15 >> 2);
            const int pi = (pb * 171) >> 11;   // pb / 12
            const int pj = pb - 12 * pi;
            const int base_e = (2 * pi + (sub >> 1)) * 28 + 2 * pj;   // even
            const ushort* p0 = srcImg + base_e;
            union { bf16x8 v; uint u[4]; } A;
            A.u[0] = *(const uint*)(p0 + offr[0]);
            A.u[1] = *(const uint*)(p0 + offr[1]);
            A.u[2] = *(const uint*)(p0 + offr[2]);
            A.u[3] = *(const uint*)(p0 + offr[3]);
            f32x4 z = {0.f, 0.f, 0.f, 0.f};
            f32x4 ce0 = __builtin_amdgcn_mfma_f32_16x16x32_bf16(A.v, bw1[0],  z, 0, 0, 0);
            f32x4 co0 = __builtin_amdgcn_mfma_f32_16x16x32_bf16(A.v, bw1s[0], z, 0, 0, 0);
            f32x4 ce1 = __builtin_amdgcn_mfma_f32_16x16x32_bf16(A.v, bw1[1],  z, 0, 0, 0);
            f32x4 co1 = __builtin_amdgcn_mfma_f32_16x16x32_bf16(A.v, bw1s[1], z, 0, 0, 0);
            const int pbo = 4 * i + quad;
            float m0 = fmaxf(fmaxf(ce0[0], co0[1]), fmaxf(ce0[2], co0[3]));
            float m1 = fmaxf(fmaxf(ce1[0], co1[1]), fmaxf(ce1[2], co1[3]));
            s_h1[(img * 4 + g0) * 1160 + pbo * 8 + r0]     = f2bfu(fmaxf(m0 + bb1[0], 0.f));
            s_h1[(img * 4 + 2 + g0) * 1160 + pbo * 8 + r0] = f2bfu(fmaxf(m1 + bb1[1], 0.f));
        }
    }
    __syncthreads();

    // ---- conv2: 25 tap-GEMMs, K=ic=32; wave = (pool-row, n-half), 4 images
    //      4 A ds_reads + 2 coalesced B loads -> 8 MFMA per tap ----
    const int pr = wave >> 1, nh = wave & 1;
    const int sub2 = l15 & 3;
    const int ci2 = 2 * pr + (sub2 >> 1);
    const int cj2 = 2 * (l15 >> 2) + (sub2 & 1);
    const int posBase = (ci2 * 12 + cj2) * 8;

    f32x4 acc[4][2];                       // [img][ntl]
    float bb2[2];
    #pragma unroll
    for (int ntl = 0; ntl < 2; ++ntl) {
        bb2[ntl] = b2[(nh * 2 + ntl) * 16 + l15];
        #pragma unroll
        for (int img = 0; img < 4; ++img)
            acc[img][ntl] = (f32x4){0.f, 0.f, 0.f, 0.f};
    }

    #pragma unroll
    for (int tap = 0; tap < 25; ++tap) {
        const int ki = tap / 5, kj = tap % 5;          // compile-time
        const int off = (ki * 12 + kj) * 8;
        bf16x8 a[4];
        #pragma unroll
        for (int img = 0; img < 4; ++img)
            a[img] = *(const bf16x8*)&s_h1[(img * 4 + quad) * 1160 + posBase + off];
        #pragma unroll
        for (int ntl = 0; ntl < 2; ++ntl) {
            bf16x8 bf = *(const bf16x8*)((const ushort*)wc2f +
                          ((tap * 4 + nh * 2 + ntl) * 64 + lane) * 8);
            #pragma unroll
            for (int img = 0; img < 4; ++img)
                acc[img][ntl] = __builtin_amdgcn_mfma_f32_16x16x32_bf16(
                    a[img], bf, acc[img][ntl], 0, 0, 0);
        }
    }

    // D rows m = quad*4+r -> (pool row = pr, pool col = quad), max over r.
    // Write h2 FRAGMENT-MAJOR.
    #pragma unroll
    for (int img = 0; img < 4; ++img) {
        const int img_g = b0 + img;
        const size_t base = (size_t)(img_g >> 4) * 16384 + (img_g & 15) * 8;
        #pragma unroll
        for (int ntl = 0; ntl < 2; ++ntl) {
            f32x4 c = acc[img][ntl];
            float m = fmaxf(fmaxf(c[0], c[1]), fmaxf(c[2], c[3]));
            float v = fmaxf(m + bb2[ntl], 0.f);
            const int k = (nh * 2 + ntl) * 256 + l15 * 16 + pr * 4 + quad;
            h2f[base + (size_t)(k >> 5) * 512 + ((k >> 3) & 3) * 128 + (k & 7)] =
                f2bfu(v);
        }
    }
}

// Fused fc1 + fc2 + log_softmax. 1024 thr = 16 waves; block = 16 images.
// fc1: wave = 32-col strip; A/B frag-major straight from global; K-loop split
//      in registers -> 4 independent MFMA chains of 16 (2 cols x 2 k-halves).
// fc2: wave = 1 image, full-wave shuffle reduce.
__global__ __launch_bounds__(1024)
void k_fc(const ushort* __restrict__ h2f, const __hip_bfloat16* __restrict__ W3f,
          const float* __restrict__ b3, const float* __restrict__ fc2w,
          const float* __restrict__ fc2b, float* __restrict__ out) {
    __shared__ float s_h3[16 * 516];

    const int tid = threadIdx.x;
    const int wave = tid >> 6, lane = tid & 63;
    const int l15 = lane & 15, quad = lane >> 4;
    const int mBase = blockIdx.x * 16;

    f32x4 acc[2][2];                       // [ntl][khalf]
    #pragma unroll
    for (int ntl = 0; ntl < 2; ++ntl) {
        acc[ntl][0] = (f32x4){0.f, 0.f, 0.f, 0.f};
        acc[ntl][1] = (f32x4){0.f, 0.f, 0.f, 0.f};
    }

    const ushort* aP  = h2f + (size_t)blockIdx.x * 16384 + lane * 8;
    const ushort* bP0 = (const ushort*)W3f + ((size_t)(wave * 2)     * 16384 + lane * 8);
    const ushort* bP1 = (const ushort*)W3f + ((size_t)(wave * 2 + 1) * 16384 + lane * 8);
    #pragma unroll 4
    for (int kt = 0; kt < 16; ++kt) {
        bf16x8 a0  = *(const bf16x8*)(aP  + kt * 512);
        bf16x8 a1  = *(const bf16x8*)(aP  + (kt + 16) * 512);
        bf16x8 b00 = *(const bf16x8*)(bP0 + kt * 512);
        bf16x8 b01 = *(const bf16x8*)(bP0 + (kt + 16) * 512);
        bf16x8 b10 = *(const bf16x8*)(bP1 + kt * 512);
        bf16x8 b11 = *(const bf16x8*)(bP1 + (kt + 16) * 512);
        acc[0][0] = __builtin_amdgcn_mfma_f32_16x16x32_bf16(a0, b00, acc[0][0], 0, 0, 0);
        acc[1][0] = __builtin_amdgcn_mfma_f32_16x16x32_bf16(a0, b10, acc[1][0], 0, 0, 0);
        acc[0][1] = __builtin_amdgcn_mfma_f32_16x16x32_bf16(a1, b01, acc[0][1], 0, 0, 0);
        acc[1][1] = __builtin_amdgcn_mfma_f32_16x16x32_bf16(a1, b11, acc[1][1], 0, 0, 0);
    }

    #pragma unroll
    for (int ntl = 0; ntl < 2; ++ntl) {
        int col = wave * 32 + ntl * 16 + l15;
        float bb = b3[col];
        #pragma unroll
        for (int r = 0; r < 4; ++r) {
            float v = acc[ntl][0][r] + acc[ntl][1][r];
            s_h3[(quad * 4 + r) * 516 + col] = fmaxf(v + bb, 0.f);
        }
    }
    __syncthreads();

    // ---- fc2 + log_softmax: wave handles image `wave` ----
    const float* hrow = &s_h3[wave * 516];
    float4 h0 = *(const float4*)&hrow[lane * 8];
    float4 h1 = *(const float4*)&hrow[lane * 8 + 4];
    float lg[10];
    #pragma unroll
    for (int c = 0; c < 10; ++c) {
        float4 w0 = *(const float4*)&fc2w[c * 512 + lane * 8];
        float4 w1 = *(const float4*)&fc2w[c * 512 + lane * 8 + 4];
        float s = h0.x * w0.x + h0.y * w0.y + h0.z * w0.z + h0.w * w0.w
                + h1.x * w1.x + h1.y * w1.y + h1.z * w1.z + h1.w * w1.w;
        s += __shfl_down(s, 32);
        s += __shfl_down(s, 16);
        s += __shfl_down(s, 8);
        s += __shfl_down(s, 4);
        s += __shfl_down(s, 2);
        s += __shfl_down(s, 1);
        lg[c] = s;
    }
    if (lane == 0) {
        float mx = -1e30f;
        #pragma unroll
        for (int c = 0; c < 10; ++c) { lg[c] += fc2b[c]; mx = fmaxf(mx, lg[c]); }
        float sum = 0.f;
        #pragma unroll
        for (int c = 0; c < 10; ++c) sum += expf(lg[c] - mx);
        float lse = mx + logf(sum);
        #pragma unroll
        for (int c = 0; c < 10; ++c)
            out[(size_t)(mBase + wave) * 10 + c] = lg[c] - lse;
    }
}

extern "C" void kernel_launch(void* const* d_in, const int* in_sizes, int n_in,
                              void* d_out, int out_size, void* d_ws, size_t ws_size,
                              hipStream_t stream) {
    const float* x    = (const float*)d_in[0];
    const int*   hi1  = (const int*)d_in[1];
    const int*   hi2  = (const int*)d_in[2];
    const int*   hi3  = (const int*)d_in[3];
    const float* s1   = (const float*)d_in[4];
    const float* s2   = (const float*)d_in[5];
    const float* s3   = (const float*)d_in[6];
    const float* w1   = (const float*)d_in[7];
    const float* b1   = (const float*)d_in[8];
    const float* w2   = (const float*)d_in[9];
    const float* b2   = (const float*)d_in[10];
    const float* w3   = (const float*)d_in[11];
    const float* b3   = (const float*)d_in[12];
    const float* fc2w = (const float*)d_in[13];
    const float* fc2b = (const float*)d_in[14];
    float* out = (float*)d_out;

    const int B = in_sizes[0] / 784;   // 4096

    char* ws = (char*)d_ws;
    __hip_bfloat16* wc1f = (__hip_bfloat16*)(ws + 0);
    __hip_bfloat16* wc1s = (__hip_bfloat16*)(ws + 2048);
    __hip_bfloat16* wc2f = (__hip_bfloat16*)(ws + 4096);
    __hip_bfloat16* W3f  = (__hip_bfloat16*)(ws + 106496);
    ushort*         h2f  = (ushort*)(ws + 1155072);

    k_reconstruct<<<(72192 + 255) / 256, 256, 0, stream>>>(
        w1, w2, w3, hi1, hi2, hi3, s1, s2, s3, wc1f, wc1s, wc2f, W3f);
    k_conv<<<B / 4, 512, 0, stream>>>(x, wc1f, wc1s, wc2f, b1, b2, h2f);
    k_fc<<<B / 16, 1024, 0, stream>>>(h2f, W3f, b3, fc2w, fc2b, out);
}